// Round 5
// baseline (719.349 us; speedup 1.0000x reference)
//
#include <hip/hip_runtime.h>

constexpr int Bn = 2, C = 21, H = 256, W = 256, HW = H * W;
constexpr int K = 5, K2 = 25;
constexpr int TW = 32, TH = 8;            // 256 pixels per block
constexpr int LH = TH + 4, LW = TW + 4;   // 12 x 36 staged tile
constexpr int NCELL = LH * LW;            // 432
constexpr int CA = 11;                    // half0 owns c0..10, half1 owns c11..20

// ---------------------------------------------------------------------------
// Prep: bilateral weights only. w[b][k][p] = spatial_w[k] * color_w(b,k,p).
// ---------------------------------------------------------------------------
__global__ __launch_bounds__(256) void prep_kernel(
        const float* __restrict__ img, float* __restrict__ w) {
    int idx = blockIdx.x * 256 + threadIdx.x;
    if (idx >= Bn * HW) return;
    int b = idx / HW, p = idx % HW;
    int y = p / W, x = p % W;
    const float* im = img + (size_t)b * 3 * HW;
    float c0 = im[p], c1 = im[HW + p], c2 = im[2 * HW + p];
    float S = 0.f;
#pragma unroll
    for (int k = 0; k < K2; ++k) {
        int dy = k / K - 2, dx = k % K - 2;
        S += __expf(-(float)(dy * dy + dx * dx) * 0.02f);   // sigma_s = 5
    }
    float invS = 1.f / S;
#pragma unroll
    for (int k = 0; k < K2; ++k) {
        int dy = k / K - 2, dx = k % K - 2;
        int ny = y + dy, nx = x + dx;
        float d0 = -c0, d1 = -c1, d2 = -c2;                 // zero-padded nbr
        if ((unsigned)ny < H && (unsigned)nx < W) {
            int np = ny * W + nx;
            d0 += im[np]; d1 += im[HW + np]; d2 += im[2 * HW + np];
        }
        float sk = __expf(-(float)(dy * dy + dx * dx) * 0.02f);
        float cw = __expf(-(d0 * d0 + d1 * d1 + d2 * d2) * 50.f);  // sigma_c=0.1
        w[((size_t)b * K2 + k) * HW + p] = sk * invS * cw;
    }
}

// ---------------------------------------------------------------------------
// One mean-field iteration. 512 threads = 2 threads/pixel (channel split;
// softmax combine = __shfl_xor(32)). init!=0: staging computes q0 =
// softmax(logits) per staged cell (no q0 global pass needed).
// Spatial gaussian (sigma=0.1) is a delta, folded as wk[12] += 1.
// compat == -I fast path (runtime-verified, block-uniform); general path
// reuses sq as the m-exchange buffer.
// ---------------------------------------------------------------------------
__global__ __launch_bounds__(512, 6) void crf_iter(
        const float* __restrict__ qin, const float* __restrict__ w,
        const float* __restrict__ logits, const float* __restrict__ compat,
        float* __restrict__ qout, int init) {
    __shared__ float sq[C][LH][LW];     // 36288 B (also m-exchange, slow path)
    __shared__ float scm[C * C];        // 1764 B

    const int b = blockIdx.z;
    const int x0 = blockIdx.x * TW, y0 = blockIdx.y * TH;
    const int tid = threadIdx.x;
    const int px = tid & 31;
    const int half = (tid >> 5) & 1;
    const int py = tid >> 6;
    const int x = x0 + px, y = y0 + py, p = y * W + x;
    const int pi = py * TW + px;
    const int cbase = half ? CA : 0;
    const int nch = half ? (C - CA) : CA;

    // ---- stage compat (+ -I check) ----
    int ok = 1;
    for (int i = tid; i < C * C; i += 512) {
        float v = compat[i];
        scm[i] = v;
        ok &= (v == ((i / C == i % C) ? -1.0f : 0.0f));
    }

    // ---- stage q tile (2-halo) ----
    if (init) {
        // q0 = softmax(logits) computed per staged cell
        if (tid < NCELL) {
            int ly = tid / LW, lx = tid % LW;
            int gy = y0 + ly - 2, gx = x0 + lx - 2;
            if ((unsigned)gy < H && (unsigned)gx < W) {
                const float* lg = logits + (size_t)b * C * HW + gy * W + gx;
                float zz[C], mx = -1e30f;
#pragma unroll
                for (int c = 0; c < C; ++c) {
                    zz[c] = lg[(size_t)c * HW];
                    mx = fmaxf(mx, zz[c]);
                }
                float s = 0.f;
#pragma unroll
                for (int c = 0; c < C; ++c) { zz[c] = __expf(zz[c] - mx); s += zz[c]; }
                float inv = 1.f / s;
#pragma unroll
                for (int c = 0; c < C; ++c) sq[c][ly][lx] = zz[c] * inv;
            } else {
#pragma unroll
                for (int c = 0; c < C; ++c) sq[c][ly][lx] = 0.f;
            }
        }
    } else {
        const float* qb_ = qin + (size_t)b * C * HW;
        for (int i = tid; i < C * NCELL; i += 512) {
            int c = i / NCELL, r = i % NCELL;
            int ly = r / LW, lx = r % LW;
            int gy = y0 + ly - 2, gx = x0 + lx - 2;
            float v = 0.f;
            if ((unsigned)gy < H && (unsigned)gx < W)
                v = qb_[(size_t)c * HW + gy * W + gx];
            sq[c][ly][lx] = v;
        }
    }

    // ---- per-pixel loads (in flight across the barrier) ----
    float wk[K2];
#pragma unroll
    for (int k = 0; k < K2; ++k) wk[k] = w[((size_t)b * K2 + k) * HW + p];
    wk[12] += 1.0f;                     // fold identity (delta) spatial conv
    const float* lgp = logits + (size_t)b * C * HW + p;
    float lgv[CA];
#pragma unroll
    for (int cc = 0; cc < CA; ++cc)
        lgv[cc] = (cc < nch) ? lgp[(size_t)(cbase + cc) * HW] : 0.f;

    const int fast = __syncthreads_and(ok);

    // ---- bilateral message passing (own channels only) ----
    float m[CA];
#pragma unroll
    for (int cc = 0; cc < CA; ++cc) {
        m[cc] = 0.f;
        if (cc < nch) {
            int c = cbase + cc;
            float acc = 0.f;
#pragma unroll
            for (int k = 0; k < K2; ++k)
                acc += wk[k] * sq[c][py + k / K][px + k % K];
            m[cc] = acc;
        }
    }

    // ---- compatibility transform ----
    float z[CA];
    if (fast) {                          // compat == -I: z = logits + m
#pragma unroll
        for (int cc = 0; cc < CA; ++cc) z[cc] = lgv[cc] + m[cc];
    } else {                             // general matvec; reuse sq as exchange
        __syncthreads();                 // all tap reads done
        float* smf = &sq[0][0][0];       // [256][C] region (21.5 KB < 36 KB)
#pragma unroll
        for (int cc = 0; cc < CA; ++cc)
            if (cc < nch) smf[pi * C + cbase + cc] = m[cc];
        __syncthreads();
        float mall[C];
#pragma unroll
        for (int j = 0; j < C; ++j) mall[j] = smf[pi * C + j];
#pragma unroll
        for (int cc = 0; cc < CA; ++cc) {
            float pw = 0.f;
#pragma unroll
            for (int j = 0; j < C; ++j) pw += scm[(cbase + cc) * C + j] * mall[j];
            z[cc] = lgv[cc] - pw;
        }
    }

    // ---- softmax across the two channel-halves (lane l <-> l+32) ----
    float mx = -1e30f;
#pragma unroll
    for (int cc = 0; cc < CA; ++cc) if (cc < nch) mx = fmaxf(mx, z[cc]);
    mx = fmaxf(mx, __shfl_xor(mx, 32));
    float s = 0.f;
#pragma unroll
    for (int cc = 0; cc < CA; ++cc)
        if (cc < nch) { z[cc] = __expf(z[cc] - mx); s += z[cc]; }
    s += __shfl_xor(s, 32);
    float inv = 1.f / s;
    float* qo = qout + (size_t)b * C * HW + p;
#pragma unroll
    for (int cc = 0; cc < CA; ++cc)
        if (cc < nch) qo[(size_t)(cbase + cc) * HW] = z[cc] * inv;
}

// ---------------------------------------------------------------------------
extern "C" void kernel_launch(void* const* d_in, const int* in_sizes, int n_in,
                              void* d_out, int out_size, void* d_ws, size_t ws_size,
                              hipStream_t stream) {
    const float* logits = (const float*)d_in[0];
    const float* img    = (const float*)d_in[1];
    // d_in[2] = gt_edges (dead code in reference)
    const float* compat = (const float*)d_in[3];
    float* out = (float*)d_out;

    float* qa   = (float*)d_ws;                     // Bn*C*HW floats
    float* qb   = qa + (size_t)Bn * C * HW;         // Bn*C*HW floats
    float* wbuf = qb + (size_t)Bn * C * HW;         // Bn*K2*HW floats

    int nb = (Bn * HW + 255) / 256;
    prep_kernel<<<nb, 256, 0, stream>>>(img, wbuf);

    dim3 g(W / TW, H / TH, Bn);                     // 8 x 32 x 2 = 512 blocks
    crf_iter<<<g, 512, 0, stream>>>(qa, wbuf, logits, compat, qb, 1);  // q0 inline
    crf_iter<<<g, 512, 0, stream>>>(qb, wbuf, logits, compat, qa, 0);
    crf_iter<<<g, 512, 0, stream>>>(qa, wbuf, logits, compat, qb, 0);
    crf_iter<<<g, 512, 0, stream>>>(qb, wbuf, logits, compat, qa, 0);
    crf_iter<<<g, 512, 0, stream>>>(qa, wbuf, logits, compat, out, 0);
}

// Round 6
// 85.274 us; speedup vs baseline: 8.4358x; 8.4358x over previous
//
#include <hip/hip_runtime.h>

constexpr int Bn = 2, C = 21, H = 256, W = 256, HW = H * W;
constexpr int K = 5, K2 = 25;
constexpr int TW = 32, TH = 8;            // 256 pixels per block
constexpr int LH = TH + 4, LW = TW + 4;   // 12 x 36 staged tile
constexpr int NCELL = LH * LW;            // 432
constexpr int CQ = 6;                     // channel quads (C padded to 24)
constexpr int NCH0 = 12;                  // half0 owns c0..11 (quads 0-2)
constexpr int NCH1 = 9;                   // half1 owns c12..20 (quads 3-5)

// ---------------------------------------------------------------------------
// Prep: bilateral weights. w[b][k][p] = spatial_w[k] * color_w(b,k,p).
// ---------------------------------------------------------------------------
__global__ __launch_bounds__(256) void prep_kernel(
        const float* __restrict__ img, float* __restrict__ w) {
    int idx = blockIdx.x * 256 + threadIdx.x;
    if (idx >= Bn * HW) return;
    int b = idx / HW, p = idx % HW;
    int y = p / W, x = p % W;
    const float* im = img + (size_t)b * 3 * HW;
    float c0 = im[p], c1 = im[HW + p], c2 = im[2 * HW + p];
    float S = 0.f;
#pragma unroll
    for (int k = 0; k < K2; ++k) {
        int dy = k / K - 2, dx = k % K - 2;
        S += __expf(-(float)(dy * dy + dx * dx) * 0.02f);   // sigma_s = 5
    }
    float invS = 1.f / S;
#pragma unroll
    for (int k = 0; k < K2; ++k) {
        int dy = k / K - 2, dx = k % K - 2;
        int ny = y + dy, nx = x + dx;
        float d0 = -c0, d1 = -c1, d2 = -c2;                 // zero-padded nbr
        if ((unsigned)ny < H && (unsigned)nx < W) {
            int np = ny * W + nx;
            d0 += im[np]; d1 += im[HW + np]; d2 += im[2 * HW + np];
        }
        float sk = __expf(-(float)(dy * dy + dx * dx) * 0.02f);
        float cw = __expf(-(d0 * d0 + d1 * d1 + d2 * d2) * 50.f);  // sigma_c=0.1
        w[((size_t)b * K2 + k) * HW + p] = sk * invS * cw;
    }
}

// ---------------------------------------------------------------------------
// One mean-field iteration. 512 threads = 2 threads/pixel.
// LDS layout: channel-quad float4 tiles sq4[quad][ly][lx] -> each tap is
// 3x ds_read_b128 per thread (conflict-free 16B lane stride) instead of
// 11x ds_read_b32. Spatial gaussian (sigma=0.1) is a delta => wk[12] += 1.
// compat == -I fast path (runtime-verified, block-uniform).
// init!=0: staging computes q0 = softmax(logits) per cell (no q0 pass).
// ---------------------------------------------------------------------------
__global__ __launch_bounds__(512, 4) void crf_iter(
        const float* __restrict__ qin, const float* __restrict__ w,
        const float* __restrict__ logits, const float* __restrict__ compat,
        float* __restrict__ qout, int init) {
    __shared__ float4 sq4[CQ][LH][LW];   // 41472 B (also m-exchange, slow path)
    __shared__ float scm[C * C];         // 1764 B

    const int b = blockIdx.z;
    const int x0 = blockIdx.x * TW, y0 = blockIdx.y * TH;
    const int tid = threadIdx.x;
    const int px = tid & 31;
    const int half = (tid >> 5) & 1;
    const int py = tid >> 6;
    const int x = x0 + px, y = y0 + py, p = y * W + x;
    const int pi = py * TW + px;
    const int qoff = half * 3;
    const int cbase = half ? NCH0 : 0;
    const int nch = half ? NCH1 : NCH0;

    // ---- stage compat (+ -I check) ----
    int ok = 1;
    for (int i = tid; i < C * C; i += 512) {
        float v = compat[i];
        scm[i] = v;
        ok &= (v == ((i / C == i % C) ? -1.0f : 0.0f));
    }

    float* sqf = (float*)&sq4[0][0][0];

    // ---- stage q tile (2-halo) in quad-interleaved layout ----
    if (init) {
        if (tid < NCELL) {
            int ly = tid / LW, lx = tid % LW;
            int gy = y0 + ly - 2, gx = x0 + lx - 2;
            float vals[24];
            if ((unsigned)gy < H && (unsigned)gx < W) {
                const float* lg = logits + (size_t)b * C * HW + gy * W + gx;
                float zz[C], mx = -1e30f;
#pragma unroll
                for (int c = 0; c < C; ++c) {
                    zz[c] = lg[(size_t)c * HW];
                    mx = fmaxf(mx, zz[c]);
                }
                float s = 0.f;
#pragma unroll
                for (int c = 0; c < C; ++c) { zz[c] = __expf(zz[c] - mx); s += zz[c]; }
                float inv = 1.f / s;
#pragma unroll
                for (int c = 0; c < 24; ++c) vals[c] = (c < C) ? zz[c] * inv : 0.f;
            } else {
#pragma unroll
                for (int c = 0; c < 24; ++c) vals[c] = 0.f;
            }
#pragma unroll
            for (int c = 0; c < 24; ++c)
                sqf[((c >> 2) * NCELL + tid) * 4 + (c & 3)] = vals[c];
        }
    } else {
        const float* qsrc = qin + (size_t)b * C * HW;
        for (int i = tid; i < CQ * NCELL; i += 512) {
            int g = i / NCELL, r = i % NCELL;
            int ly = r / LW, lx = r % LW;
            int gy = y0 + ly - 2, gx = x0 + lx - 2;
            float4 v = make_float4(0.f, 0.f, 0.f, 0.f);
            if ((unsigned)gy < H && (unsigned)gx < W) {
                const float* qp = qsrc + gy * W + gx;
                int c0 = 4 * g;
                v.x = qp[(size_t)c0 * HW];
                v.y = (c0 + 1 < C) ? qp[(size_t)(c0 + 1) * HW] : 0.f;
                v.z = (c0 + 2 < C) ? qp[(size_t)(c0 + 2) * HW] : 0.f;
                v.w = (c0 + 3 < C) ? qp[(size_t)(c0 + 3) * HW] : 0.f;
            }
            sq4[g][ly][lx] = v;
        }
    }

    // ---- per-pixel loads (issued before the barrier, in flight across it) --
    float wk[K2];
#pragma unroll
    for (int k = 0; k < K2; ++k) wk[k] = w[((size_t)b * K2 + k) * HW + p];
    wk[12] += 1.0f;                     // fold identity (delta) spatial conv
    const float* lgp = logits + (size_t)b * C * HW + p;
    float lgv[NCH0];
#pragma unroll
    for (int cc = 0; cc < NCH0; ++cc)
        lgv[cc] = (cc < nch) ? lgp[(size_t)(cbase + cc) * HW] : 0.f;

    const int fast = __syncthreads_and(ok);

    // ---- bilateral message passing: 25 taps x 3 quad reads ----
    float mreg[NCH0];
#pragma unroll
    for (int i = 0; i < NCH0; ++i) mreg[i] = 0.f;
#pragma unroll
    for (int k = 0; k < K2; ++k) {
        const int ly = py + k / K, lx = px + k % K;
        const float wv = wk[k];
#pragma unroll
        for (int g = 0; g < 3; ++g) {
            float4 t = sq4[qoff + g][ly][lx];
            mreg[4 * g + 0] += wv * t.x;
            mreg[4 * g + 1] += wv * t.y;
            mreg[4 * g + 2] += wv * t.z;
            mreg[4 * g + 3] += wv * t.w;
        }
    }

    // ---- compatibility transform ----
    float z[NCH0];
    if (fast) {                          // compat == -I: z = logits + m
#pragma unroll
        for (int cc = 0; cc < NCH0; ++cc) z[cc] = lgv[cc] + mreg[cc];
    } else {                             // general matvec; reuse sq4 as exchange
        __syncthreads();                 // all tap reads done
        float* smf = sqf;                // [256][C] region (21.5 KB < 41 KB)
#pragma unroll
        for (int cc = 0; cc < NCH0; ++cc)
            if (cc < nch) smf[pi * C + cbase + cc] = mreg[cc];
        __syncthreads();
        float mall[C];
#pragma unroll
        for (int j = 0; j < C; ++j) mall[j] = smf[pi * C + j];
#pragma unroll
        for (int cc = 0; cc < NCH0; ++cc) {
            float pw = 0.f;
#pragma unroll
            for (int j = 0; j < C; ++j) pw += scm[(cbase + cc) * C + j] * mall[j];
            z[cc] = lgv[cc] - pw;
        }
    }

    // ---- softmax across the two channel-halves (lane l <-> l+32) ----
    float mx = -1e30f;
#pragma unroll
    for (int cc = 0; cc < NCH0; ++cc) if (cc < nch) mx = fmaxf(mx, z[cc]);
    mx = fmaxf(mx, __shfl_xor(mx, 32));
    float s = 0.f;
#pragma unroll
    for (int cc = 0; cc < NCH0; ++cc)
        if (cc < nch) { z[cc] = __expf(z[cc] - mx); s += z[cc]; }
    s += __shfl_xor(s, 32);
    float inv = 1.f / s;
    float* qo = qout + (size_t)b * C * HW + p;
#pragma unroll
    for (int cc = 0; cc < NCH0; ++cc)
        if (cc < nch) qo[(size_t)(cbase + cc) * HW] = z[cc] * inv;
}

// ---------------------------------------------------------------------------
extern "C" void kernel_launch(void* const* d_in, const int* in_sizes, int n_in,
                              void* d_out, int out_size, void* d_ws, size_t ws_size,
                              hipStream_t stream) {
    const float* logits = (const float*)d_in[0];
    const float* img    = (const float*)d_in[1];
    // d_in[2] = gt_edges (dead code in reference)
    const float* compat = (const float*)d_in[3];
    float* out = (float*)d_out;

    float* qa   = (float*)d_ws;                     // Bn*C*HW floats
    float* qb   = qa + (size_t)Bn * C * HW;         // Bn*C*HW floats
    float* wbuf = qb + (size_t)Bn * C * HW;         // Bn*K2*HW floats

    int nb = (Bn * HW + 255) / 256;
    prep_kernel<<<nb, 256, 0, stream>>>(img, wbuf);

    dim3 g(W / TW, H / TH, Bn);                     // 8 x 32 x 2 = 512 blocks
    crf_iter<<<g, 512, 0, stream>>>(qa, wbuf, logits, compat, qb, 1);  // q0 inline
    crf_iter<<<g, 512, 0, stream>>>(qb, wbuf, logits, compat, qa, 0);
    crf_iter<<<g, 512, 0, stream>>>(qa, wbuf, logits, compat, qb, 0);
    crf_iter<<<g, 512, 0, stream>>>(qb, wbuf, logits, compat, qa, 0);
    crf_iter<<<g, 512, 0, stream>>>(qa, wbuf, logits, compat, out, 0);
}